// Round 1
// 3011.840 us; speedup vs baseline: 1.0689x; 1.0689x over previous
//
#include <hip/hip_runtime.h>
#include <hip/hip_bf16.h>

using bf16 = __hip_bfloat16;
typedef __bf16 bf16x8 __attribute__((ext_vector_type(8)));
typedef float f32x4 __attribute__((ext_vector_type(4)));

#define N_CELLS 3000
#define N_GENES 1000
#define M_NODES 4000
#define NP 3072
#define MP 4096
#define CHMAX 1024   // GEMM1 output-chunk columns

// dual-mode scalar read: inputs are f32 (sniffed) or bf16 (hedge)
__device__ __forceinline__ float rdv(const void* p, size_t i, int isbf) {
    if (isbf) return (float)((const bf16*)p)[i];
    return ((const float*)p)[i];
}

__device__ __forceinline__ void async_copy16(const bf16* g, bf16* l) {
    __builtin_amdgcn_global_load_lds((const __attribute__((address_space(1))) void*)g,
                                     (__attribute__((address_space(3))) void*)l,
                                     16, 0, 0);
}

// X ~ U[0,1): as bf16 every word's low16 < 0x3F80 (~100%); as f32 ~25%.
__global__ void sniff_dtype(const unsigned int* __restrict__ X, int* __restrict__ flag)
{
    __shared__ int cnt[4];
    int t = threadIdx.x;
    int c = 0;
    for (int i = t; i < 2048; i += 256)
        if ((X[i] & 0xFFFFu) < 0x3F80u) c++;
    #pragma unroll
    for (int off = 32; off > 0; off >>= 1) c += __shfl_down(c, off);
    if ((t & 63) == 0) cnt[t >> 6] = c;
    __syncthreads();
    if (t == 0) flag[0] = (cnt[0] + cnt[1] + cnt[2] + cnt[3] > 1536) ? 1 : 0;
}

// ---------------------------------------------------------------------------
// NT GEMM with async global->LDS staging (m97 pattern): C[i,j] =
// sum_k A[i,k]*B[j,k], 128x128 tile, K%32==0, bf16 in, OutT out.
// RELU_BIAS: C=relu(C+bias[j]). TRANS_OUT: store C[j,i]. SCALE_ROW: *rowinv[i].
// ---------------------------------------------------------------------------
template<bool RELU_BIAS, bool TRANS_OUT, bool SCALE_ROW, typename OutT>
__global__ __launch_bounds__(256, 2)
void gemm_nt(const bf16* __restrict__ A, int lda,
             const bf16* __restrict__ B, int ldb,
             const bf16* __restrict__ bias,
             const float* __restrict__ rowinv,
             OutT* __restrict__ C, int ldc,
             int K, int mBound, int nBound)
{
    __shared__ __align__(16) bf16 As[128 * 32];
    __shared__ __align__(16) bf16 Bs[128 * 32];
    const int tid  = threadIdx.x;
    const int wave = tid >> 6;
    const int lane = tid & 63;
    const int i0 = blockIdx.y * 128;
    const int j0 = blockIdx.x * 128;

    // async staging: wave w covers rows [w*32, w*32+32); lane -> (srow, 8-elem k)
    // HW writes lane i's 16B at (wave-uniform LDS base) + i*16 — layout matches.
    const int srow = lane >> 2;          // 0..15
    const int sk   = (lane & 3) * 8;     // 0,8,16,24
    const bf16* gA0 = A + (size_t)(i0 + wave * 32 + srow) * lda + sk;
    const bf16* gA1 = gA0 + (size_t)16 * lda;
    const bf16* gB0 = B + (size_t)(j0 + wave * 32 + srow) * ldb + sk;
    const bf16* gB1 = gB0 + (size_t)16 * ldb;
    bf16* lA0 = &As[(wave * 32) * 32];
    bf16* lA1 = &As[(wave * 32 + 16) * 32];
    bf16* lB0 = &Bs[(wave * 32) * 32];
    bf16* lB1 = &Bs[(wave * 32 + 16) * 32];

    const int wm = (wave >> 1) * 64;
    const int wn = (wave & 1) * 64;
    const int fr = lane & 15;
    const int fk = (lane >> 4) * 8;

    f32x4 acc[4][4] = {};

    for (int kt = 0; kt < K; kt += 32) {
        async_copy16(gA0 + kt, lA0);
        async_copy16(gA1 + kt, lA1);
        async_copy16(gB0 + kt, lB0);
        async_copy16(gB1 + kt, lB1);
        __syncthreads();   // drains vmcnt -> staged data visible

        bf16x8 af[4], bfv[4];
        #pragma unroll
        for (int t = 0; t < 4; t++) {
            af[t]  = *(const bf16x8*)&As[(wm + t * 16 + fr) * 32 + fk];
            bfv[t] = *(const bf16x8*)&Bs[(wn + t * 16 + fr) * 32 + fk];
        }
        #pragma unroll
        for (int mt = 0; mt < 4; mt++)
            #pragma unroll
            for (int nt = 0; nt < 4; nt++)
                acc[mt][nt] = __builtin_amdgcn_mfma_f32_16x16x32_bf16(
                    af[mt], bfv[nt], acc[mt][nt], 0, 0, 0);
        __syncthreads();   // all reads done before next stage overwrites
    }

    // C/D mapping: col(n)=lane&15, row(m)=(lane>>4)*4+reg
    const int ci = (lane >> 4) * 4;
    const int cj = lane & 15;
    #pragma unroll
    for (int nt = 0; nt < 4; nt++) {
        const int gj = j0 + wn + nt * 16 + cj;
        if (gj >= nBound) continue;
        float bv = 0.f;
        if (RELU_BIAS) bv = (float)bias[gj];
        #pragma unroll
        for (int mt = 0; mt < 4; mt++) {
            #pragma unroll
            for (int rg = 0; rg < 4; rg++) {
                const int gi = i0 + wm + mt * 16 + ci + rg;
                if (gi < mBound) {
                    float v = acc[mt][nt][rg];
                    if (RELU_BIAS) { v += bv; v = v > 0.f ? v : 0.f; }
                    if (SCALE_ROW) v *= rowinv[gi];
                    if (TRANS_OUT) C[(size_t)gj * ldc + gi] = (OutT)v;
                    else           C[(size_t)gi * ldc + gj] = (OutT)v;
                }
            }
        }
    }
}

// dst (rp x cp) bf16 = src (r x c, dual-mode) zero-padded
__global__ void padcopy(const void* __restrict__ src, int r, int c,
                        bf16* __restrict__ dst, int rp, int cp,
                        const int* __restrict__ flag)
{
    const int isbf = flag[0];
    long idx = (long)blockIdx.x * 256 + threadIdx.x;
    if (idx >= (long)rp * cp) return;
    int i = (int)(idx / cp), j = (int)(idx % cp);
    float v = 0.f;
    if (i < r && j < c) v = rdv(src, (size_t)i * c + j, isbf);
    dst[idx] = (bf16)v;
}

// XT (np x np bf16) = transpose of src (n x n, dual-mode), zero-padded.
// 32x32 LDS tile: both the global read and the global write are coalesced.
__global__ void padcopy_T(const void* __restrict__ src, int n,
                          bf16* __restrict__ dst, int np,
                          const int* __restrict__ flag)
{
    __shared__ float t[32][33];
    const int isbf = flag[0];
    const int tx = threadIdx.x & 31;
    const int ty = threadIdx.x >> 5;     // 0..7
    const int i0 = blockIdx.y * 32;      // output row block (i = src col)
    const int k0 = blockIdx.x * 32;      // output col block (k = src row)
    #pragma unroll
    for (int q = 0; q < 4; q++) {        // stage src[k0+r][i0+tx]
        int k = k0 + ty + q * 8;
        float v = 0.f;
        if (k < n && i0 + tx < n) v = rdv(src, (size_t)k * n + i0 + tx, isbf);
        t[ty + q * 8][tx] = v;
    }
    __syncthreads();
    #pragma unroll
    for (int q = 0; q < 4; q++) {        // write dst[i0+r][k0+tx] = src[k0+tx][i0+r]
        int i = ty + q * 8;
        dst[(size_t)(i0 + i) * np + k0 + tx] = (bf16)t[tx][i];
    }
}

__global__ void zero_f32(float* __restrict__ p, int n)
{
    int i = blockIdx.x * 256 + threadIdx.x;
    if (i < n) p[i] = 0.f;
}

// s[i] += sum_o Zt[o,i]*vt[oBase+o]; r likewise. Zt chunk-local (ld = nPad).
__global__ void scores_accum(const bf16* __restrict__ Zt, int ld,
                             int oBase, int oCount,
                             const void* __restrict__ vt, const void* __restrict__ vr,
                             float* __restrict__ s, float* __restrict__ r,
                             const int* __restrict__ flag)
{
    const int isbf = flag[0];
    const int i = blockIdx.x * 256 + threadIdx.x;
    const int o0 = blockIdx.y * 256;
    int o1 = o0 + 256; if (o1 > oCount) o1 = oCount;
    if (o0 >= o1) return;
    float as = 0.f, ar = 0.f;
    for (int o = o0; o < o1; o++) {
        float z = (float)Zt[(size_t)o * ld + i];
        as += z * rdv(vt, oBase + o, isbf);
        ar += z * rdv(vr, oBase + o, isbf);
    }
    atomicAdd(&s[i], as);
    atomicAdd(&r[i], ar);
}

__global__ void scores_bias(float* __restrict__ s, float* __restrict__ r,
                            const void* __restrict__ vtb, const void* __restrict__ vrb,
                            const int* __restrict__ flag)
{
    const int isbf = flag[0];
    int i = blockIdx.x * 256 + threadIdx.x;
    s[i] += rdv(vtb, 0, isbf);
    r[i] += rdv(vrb, 0, isbf);
}

// Full E: E[i,j] = exp(sigmoid(A[i,j]*s[j] + A[j,i]*r[i])) (i,j<n else 0),
// all nPad x nPad written; fp32 row sums accumulated via per-tile atomics.
__global__ void e_pass(const void* __restrict__ A, int n,
                       const float* __restrict__ s, const float* __restrict__ r,
                       bf16* __restrict__ E, int ldE, float* __restrict__ rowsum,
                       const int* __restrict__ flag)
{
    __shared__ float t2[32][33];
    const int isbf = flag[0];
    const int tx = threadIdx.x & 31;
    const int ty = threadIdx.x >> 5;
    const int i0 = blockIdx.y * 32;
    const int j0 = blockIdx.x * 32;
    #pragma unroll
    for (int q = 0; q < 4; q++) {        // stage A[j0+a][i0+tx] (transposed access)
        int jr = j0 + ty + q * 8;
        float v = 0.f;
        if (jr < n && i0 + tx < n) v = rdv(A, (size_t)jr * n + i0 + tx, isbf);
        t2[ty + q * 8][tx] = v;
    }
    __syncthreads();
    #pragma unroll
    for (int q = 0; q < 4; q++) {
        const int a  = ty + q * 8;
        const int gi = i0 + a;
        const int gj = j0 + tx;
        float e = 0.f;
        if (gi < n && gj < n) {
            float aij = rdv(A, (size_t)gi * n + gj, isbf);
            float x = aij * s[gj] + t2[tx][a] * r[gi];
            float sig = 1.f / (1.f + expf(-x));
            e = expf(sig);
        }
        E[(size_t)gi * ldE + gj] = (bf16)e;
        float p = e;
        #pragma unroll
        for (int off = 16; off > 0; off >>= 1) p += __shfl_down(p, off, 32);
        if (tx == 0 && gi < n) atomicAdd(&rowsum[gi], p);
    }
}

// inv over ALL nPad rows; pad rows (rowsum==0) -> 0.
__global__ void finalize_inv(const float* __restrict__ rowsum, float* __restrict__ inv, int nPad)
{
    int i = blockIdx.x * 256 + threadIdx.x;
    if (i < nPad) {
        float v = rowsum[i];
        inv[i] = v > 0.f ? 1.f / v : 0.f;
    }
}

// D (MP x 128): rows m<G from gG[c,m] (dual); rows G..M-1 from H3[m-G,c]; else 0
__global__ void build_D(const void* __restrict__ gG, const bf16* __restrict__ H3,
                        bf16* __restrict__ D, const int* __restrict__ flag)
{
    const int isbf = flag[0];
    int idx = blockIdx.x * 256 + threadIdx.x;
    int m = idx >> 7, c = idx & 127;
    float v = 0.f;
    if (c < 64) {
        if (m < N_GENES)      v = rdv(gG, (size_t)c * N_GENES + m, isbf);
        else if (m < M_NODES) v = (float)H3[(size_t)(m - N_GENES) * 128 + c];
    }
    D[idx] = (bf16)v;
}

extern "C" void kernel_launch(void* const* d_in, const int* in_sizes, int n_in,
                              void* d_out, int out_size, void* d_ws, size_t ws_size,
                              hipStream_t stream)
{
    const void* X     = d_in[0];
    const void* A_enc = d_in[1];
    const void* A_dec = d_in[2];
    const void* gG    = d_in[3];
    const void *W[7], *Wb[7], *vt[7], *vtb[7], *vr[7], *vrb[7];
    for (int l = 0; l < 7; l++) {
        W[l]   = d_in[4 + 6 * l + 0];
        Wb[l]  = d_in[4 + 6 * l + 1];
        vt[l]  = d_in[4 + 6 * l + 2];
        vtb[l] = d_in[4 + 6 * l + 3];
        vr[l]  = d_in[4 + 6 * l + 4];
        vrb[l] = d_in[4 + 6 * l + 5];
    }

    const int fop[7] = {512, 256, 128, 256, 512, 4096, 1024};
    const int fip[7] = {3072, 512, 256, 128, 256, 512, 512};
    const int foR[7] = {512, 256, 64, 256, 512, 4000, 1000};
    const int fiR[7] = {3000, 512, 256, 64, 256, 512, 512};

    // ---- workspace layout (~59 MB), small first ----
    char* ws = (char*)d_ws;
    size_t off = 0;
    auto alloc = [&](size_t bytes) -> void* {
        void* p = ws + off;
        off += (bytes + 255) & ~(size_t)255;
        return p;
    };
    int*   flag = (int*)alloc(256);
    float* sb   = (float*)alloc((size_t)MP * 4);   // sb, rb, rsum contiguous
    float* rb   = (float*)alloc((size_t)MP * 4);
    float* rsum = (float*)alloc((size_t)MP * 4);
    float* rinv = (float*)alloc((size_t)MP * 4);
    bf16* Bp[7];
    for (int l = 0; l < 7; l++) Bp[l] = (bf16*)alloc((size_t)fop[l] * 2);
    bf16* RA = (bf16*)alloc((size_t)NP * 512 * 2);   // H1 -> H3 -> D1
    bf16* RB = (bf16*)alloc((size_t)NP * 256 * 2);   // H2 -> Dd
    bf16* RC = (bf16*)alloc((size_t)MP * 512 * 2);   // D2
    bf16 *H1 = RA, *H3 = RA, *D1 = RA;
    bf16 *H2 = RB, *Dd = RB;
    bf16 *D2 = RC;
    bf16* Wp[7];
    for (int l = 0; l < 7; l++) Wp[l] = (bf16*)alloc((size_t)fop[l] * fip[l] * 2);
    bf16* ZT = (bf16*)alloc((size_t)CHMAX * MP * 2);   // 8 MB
    bf16* E  = (bf16*)alloc((size_t)MP * MP * 2);      // 32 MB
    // XT = pad(X^T) as bf16 (NP x NP, 18 MB) aliases E: it is consumed by the
    // layer-0 GEMM1 before e_pass (the first writer of E) runs.
    bf16* XT = E;

    // ---- prep ----
    sniff_dtype<<<1, 256, 0, stream>>>((const unsigned int*)X, flag);
    for (int l = 0; l < 7; l++) {
        long tot = (long)fop[l] * fip[l];
        padcopy<<<dim3((unsigned)((tot + 255) / 256)), 256, 0, stream>>>(
            W[l], foR[l], fiR[l], Wp[l], fop[l], fip[l], flag);
        padcopy<<<dim3((fop[l] + 255) / 256), 256, 0, stream>>>(
            Wb[l], 1, foR[l], Bp[l], 1, fop[l], flag);
    }
    padcopy_T<<<dim3(NP / 32, NP / 32), 256, 0, stream>>>(X, N_CELLS, XT, NP, flag);

    auto layer = [&](const bf16* Hin, int l, const void* Araw,
                     int nReal, int nPad, auto* Hout, int ldOut, int mB, int nBtot) {
        const int K = fip[l], NO = fop[l];
        const int CH = NO > CHMAX ? CHMAX : NO;
        const int nch = NO / CH;
        auto gemm1 = [&](int c) {
            gemm_nt<true, true, false, bf16><<<dim3(CH / 128, nPad / 128), 256, 0, stream>>>(
                Hin, K, Wp[l] + (size_t)c * CH * K, K, Bp[l] + c * CH, nullptr,
                ZT, nPad, K, nPad, CH);
        };
        // pass A: scores (sb, rb, rsum zeroed in one launch — contiguous)
        zero_f32<<<dim3(3 * MP / 256), 256, 0, stream>>>(sb, 3 * MP);
        for (int c = 0; c < nch; c++) {
            gemm1(c);
            int oBase = c * CH;
            int oCnt = foR[l] - oBase;
            if (oCnt > CH) oCnt = CH;
            if (oCnt > 0)
                scores_accum<<<dim3(nPad / 256, 4), 256, 0, stream>>>(
                    ZT, nPad, oBase, oCnt, vt[l], vr[l], sb, rb, flag);
        }
        scores_bias<<<dim3(nPad / 256), 256, 0, stream>>>(sb, rb, vtb[l], vrb[l], flag);
        // full E + row sums (once per layer)
        e_pass<<<dim3(nPad / 32, nPad / 32), 256, 0, stream>>>(
            Araw, nReal, sb, rb, E, nPad, rsum, flag);
        finalize_inv<<<dim3(nPad / 256), 256, 0, stream>>>(rsum, rinv, nPad);
        // pass B: Hout[:, cols] = rinv[i] * (E @ Z_chunk^T), full row grid
        for (int c = 0; c < nch; c++) {
            if (nch > 1) gemm1(c);   // ZT intact when nch==1
            int colBase = c * CH;
            int nB = nBtot - colBase;
            if (nB > CH) nB = CH;
            if (nB <= 0) continue;
            gemm_nt<false, false, true><<<dim3(CH / 128, nPad / 128), 256, 0, stream>>>(
                E, nPad, ZT, nPad, nullptr, rinv,
                Hout + colBase, ldOut, nPad, mB, nB);
        }
    };

    // encoder (H0 = X^T staged as XT by padcopy_T)
    layer(XT,      0, A_enc, N_CELLS, NP, H1, 512, NP, 512);
    layer(H1,      1, A_enc, N_CELLS, NP, H2, 256, NP, 256);
    layer(H2,      2, A_enc, N_CELLS, NP, H3, 128, NP, 128);
    // decoder input D = concat([gG, H3^T], axis=1)^T
    build_D<<<dim3((MP * 128) / 256), 256, 0, stream>>>(gG, H3, Dd, flag);
    layer(Dd, 3, A_dec, M_NODES, MP, D1, 256, MP, 256);
    layer(D1, 4, A_dec, M_NODES, MP, D2, 512, MP, 512);
    // outputs are float32 (reference dtype)
    float* outCell = (float*)d_out;
    float* outGene = outCell + (size_t)M_NODES * M_NODES;
    layer(D2, 5, A_dec, M_NODES, MP, outCell, 4000, 4000, 4000);
    layer(D2, 6, A_dec, M_NODES, MP, outGene, 1000, 4000, 1000);
}

// Round 2
// 2576.567 us; speedup vs baseline: 1.2495x; 1.1689x over previous
//
#include <hip/hip_runtime.h>
#include <hip/hip_bf16.h>

using bf16 = __hip_bfloat16;
typedef __bf16 bf16x8 __attribute__((ext_vector_type(8)));
typedef __bf16 bf16x4 __attribute__((ext_vector_type(4)));
typedef float f32x4 __attribute__((ext_vector_type(4)));
typedef unsigned short u16x4 __attribute__((ext_vector_type(4)));

#define N_CELLS 3000
#define N_GENES 1000
#define M_NODES 4000
#define NP 3072
#define MP 4096
#define CHMAX 1024   // GEMM1 output-chunk columns

// dual-mode scalar read: inputs are f32 (sniffed) or bf16 (hedge)
__device__ __forceinline__ float rdv(const void* p, size_t i, int isbf) {
    if (isbf) return (float)((const bf16*)p)[i];
    return ((const float*)p)[i];
}

// guarded 4-wide row load from dual-mode matrix (n x n), zero-padded
__device__ __forceinline__ f32x4 load4g(const void* A, int n, int row, int col, int isbf) {
    f32x4 v = {0.f, 0.f, 0.f, 0.f};
    if (row < n) {
        if (col + 3 < n) {
            if (isbf) {
                const u16x4 u = *(const u16x4*)((const unsigned short*)A + (size_t)row * n + col);
                #pragma unroll
                for (int k = 0; k < 4; k++) v[k] = __uint_as_float(((unsigned)u[k]) << 16);
            } else {
                v = *(const f32x4*)((const float*)A + (size_t)row * n + col);
            }
        } else {
            #pragma unroll
            for (int k = 0; k < 4; k++)
                if (col + k < n) v[k] = rdv(A, (size_t)row * n + col + k, isbf);
        }
    }
    return v;
}

__device__ __forceinline__ void async_copy16(const bf16* g, bf16* l) {
    __builtin_amdgcn_global_load_lds((const __attribute__((address_space(1))) void*)g,
                                     (__attribute__((address_space(3))) void*)l,
                                     16, 0, 0);
}

// X ~ U[0,1): as bf16 every word's low16 < 0x3F80 (~100%); as f32 ~25%.
__global__ void sniff_dtype(const unsigned int* __restrict__ X, int* __restrict__ flag)
{
    __shared__ int cnt[4];
    int t = threadIdx.x;
    int c = 0;
    for (int i = t; i < 2048; i += 256)
        if ((X[i] & 0xFFFFu) < 0x3F80u) c++;
    #pragma unroll
    for (int off = 32; off > 0; off >>= 1) c += __shfl_down(c, off);
    if ((t & 63) == 0) cnt[t >> 6] = c;
    __syncthreads();
    if (t == 0) flag[0] = (cnt[0] + cnt[1] + cnt[2] + cnt[3] > 1536) ? 1 : 0;
}

// ---------------------------------------------------------------------------
// NT GEMM with async global->LDS staging (m97 pattern): C[i,j] =
// sum_k A[i,k]*B[j,k], 128x128 tile, K%32==0, bf16 in, OutT out.
// RELU_BIAS: C=relu(C+bias[j]). TRANS_OUT: store C[j,i]. SCALE_ROW: *rowinv[i].
// ---------------------------------------------------------------------------
template<bool RELU_BIAS, bool TRANS_OUT, bool SCALE_ROW, typename OutT>
__global__ __launch_bounds__(256, 2)
void gemm_nt(const bf16* __restrict__ A, int lda,
             const bf16* __restrict__ B, int ldb,
             const bf16* __restrict__ bias,
             const float* __restrict__ rowinv,
             OutT* __restrict__ C, int ldc,
             int K, int mBound, int nBound)
{
    __shared__ __align__(16) bf16 As[128 * 32];
    __shared__ __align__(16) bf16 Bs[128 * 32];
    const int tid  = threadIdx.x;
    const int wave = tid >> 6;
    const int lane = tid & 63;
    const int i0 = blockIdx.y * 128;
    const int j0 = blockIdx.x * 128;

    // async staging: wave w covers rows [w*32, w*32+32); lane -> (srow, 8-elem k)
    // HW writes lane i's 16B at (wave-uniform LDS base) + i*16 — layout matches.
    const int srow = lane >> 2;          // 0..15
    const int sk   = (lane & 3) * 8;     // 0,8,16,24
    const bf16* gA0 = A + (size_t)(i0 + wave * 32 + srow) * lda + sk;
    const bf16* gA1 = gA0 + (size_t)16 * lda;
    const bf16* gB0 = B + (size_t)(j0 + wave * 32 + srow) * ldb + sk;
    const bf16* gB1 = gB0 + (size_t)16 * ldb;
    bf16* lA0 = &As[(wave * 32) * 32];
    bf16* lA1 = &As[(wave * 32 + 16) * 32];
    bf16* lB0 = &Bs[(wave * 32) * 32];
    bf16* lB1 = &Bs[(wave * 32 + 16) * 32];

    const int wm = (wave >> 1) * 64;
    const int wn = (wave & 1) * 64;
    const int fr = lane & 15;
    const int fk = (lane >> 4) * 8;

    f32x4 acc[4][4] = {};

    for (int kt = 0; kt < K; kt += 32) {
        async_copy16(gA0 + kt, lA0);
        async_copy16(gA1 + kt, lA1);
        async_copy16(gB0 + kt, lB0);
        async_copy16(gB1 + kt, lB1);
        __syncthreads();   // drains vmcnt -> staged data visible

        bf16x8 af[4], bfv[4];
        #pragma unroll
        for (int t = 0; t < 4; t++) {
            af[t]  = *(const bf16x8*)&As[(wm + t * 16 + fr) * 32 + fk];
            bfv[t] = *(const bf16x8*)&Bs[(wn + t * 16 + fr) * 32 + fk];
        }
        #pragma unroll
        for (int mt = 0; mt < 4; mt++)
            #pragma unroll
            for (int nt = 0; nt < 4; nt++)
                acc[mt][nt] = __builtin_amdgcn_mfma_f32_16x16x32_bf16(
                    af[mt], bfv[nt], acc[mt][nt], 0, 0, 0);
        __syncthreads();   // all reads done before next stage overwrites
    }

    // C/D mapping: col(n)=lane&15, row(m)=(lane>>4)*4+reg
    const int ci = (lane >> 4) * 4;
    const int cj = lane & 15;
    #pragma unroll
    for (int nt = 0; nt < 4; nt++) {
        const int gj = j0 + wn + nt * 16 + cj;
        if (gj >= nBound) continue;
        float bv = 0.f;
        if (RELU_BIAS) bv = (float)bias[gj];
        #pragma unroll
        for (int mt = 0; mt < 4; mt++) {
            #pragma unroll
            for (int rg = 0; rg < 4; rg++) {
                const int gi = i0 + wm + mt * 16 + ci + rg;
                if (gi < mBound) {
                    float v = acc[mt][nt][rg];
                    if (RELU_BIAS) { v += bv; v = v > 0.f ? v : 0.f; }
                    if (SCALE_ROW) v *= rowinv[gi];
                    if (TRANS_OUT) C[(size_t)gj * ldc + gi] = (OutT)v;
                    else           C[(size_t)gi * ldc + gj] = (OutT)v;
                }
            }
        }
    }
}

// dst (rp x cp) bf16 = src (r x c, dual-mode) zero-padded
__global__ void padcopy(const void* __restrict__ src, int r, int c,
                        bf16* __restrict__ dst, int rp, int cp,
                        const int* __restrict__ flag)
{
    const int isbf = flag[0];
    long idx = (long)blockIdx.x * 256 + threadIdx.x;
    if (idx >= (long)rp * cp) return;
    int i = (int)(idx / cp), j = (int)(idx % cp);
    float v = 0.f;
    if (i < r && j < c) v = rdv(src, (size_t)i * c + j, isbf);
    dst[idx] = (bf16)v;
}

// XT (np x np bf16) = transpose of src (n x n, dual-mode), zero-padded.
// 32x32 LDS tile: both the global read and the global write are coalesced.
__global__ void padcopy_T(const void* __restrict__ src, int n,
                          bf16* __restrict__ dst, int np,
                          const int* __restrict__ flag)
{
    __shared__ float t[32][33];
    const int isbf = flag[0];
    const int tx = threadIdx.x & 31;
    const int ty = threadIdx.x >> 5;     // 0..7
    const int i0 = blockIdx.y * 32;      // output row block (i = src col)
    const int k0 = blockIdx.x * 32;      // output col block (k = src row)
    #pragma unroll
    for (int q = 0; q < 4; q++) {        // stage src[k0+r][i0+tx]
        int k = k0 + ty + q * 8;
        float v = 0.f;
        if (k < n && i0 + tx < n) v = rdv(src, (size_t)k * n + i0 + tx, isbf);
        t[ty + q * 8][tx] = v;
    }
    __syncthreads();
    #pragma unroll
    for (int q = 0; q < 4; q++) {        // write dst[i0+r][k0+tx] = src[k0+tx][i0+r]
        int i = ty + q * 8;
        dst[(size_t)(i0 + i) * np + k0 + tx] = (bf16)t[tx][i];
    }
}

__global__ void zero_f32(float* __restrict__ p, int n)
{
    int i = blockIdx.x * 256 + threadIdx.x;
    if (i < n) p[i] = 0.f;
}

// s[i] += sum_o Zt[o,i]*vt[oBase+o]; r likewise. Zt chunk-local (ld = nPad).
__global__ void scores_accum(const bf16* __restrict__ Zt, int ld,
                             int oBase, int oCount,
                             const void* __restrict__ vt, const void* __restrict__ vr,
                             float* __restrict__ s, float* __restrict__ r,
                             const int* __restrict__ flag)
{
    const int isbf = flag[0];
    const int i = blockIdx.x * 256 + threadIdx.x;
    const int o0 = blockIdx.y * 256;
    int o1 = o0 + 256; if (o1 > oCount) o1 = oCount;
    if (o0 >= o1) return;
    float as = 0.f, ar = 0.f;
    for (int o = o0; o < o1; o++) {
        float z = (float)Zt[(size_t)o * ld + i];
        as += z * rdv(vt, oBase + o, isbf);
        ar += z * rdv(vr, oBase + o, isbf);
    }
    atomicAdd(&s[i], as);
    atomicAdd(&r[i], ar);
}

__global__ void scores_bias(float* __restrict__ s, float* __restrict__ r,
                            const void* __restrict__ vtb, const void* __restrict__ vrb,
                            const int* __restrict__ flag)
{
    const int isbf = flag[0];
    int i = blockIdx.x * 256 + threadIdx.x;
    s[i] += rdv(vtb, 0, isbf);
    r[i] += rdv(vrb, 0, isbf);
}

// ---------------------------------------------------------------------------
// Paired E-pass: block (bi<=bj) computes E tiles (I,J) and (J,I), 64x64 each.
// E[i,j] = exp(sigmoid(A[i,j]*s[j] + A[j,i]*r[i])) for i,j<n else 0.
// Each A element is fetched by exactly one block (HBM = 1x |A|).
// Transposed terms come from LDS transposes staged at stride 65
// (bank = (row+col)%32 -> 2-way = free). Fast exp via v_exp_f32 + v_rcp_f32
// (error << bf16 rounding of E).
// ---------------------------------------------------------------------------
__global__ __launch_bounds__(256)
void e_pass_pair(const void* __restrict__ A, int n,
                 const float* __restrict__ s, const float* __restrict__ r,
                 bf16* __restrict__ E, int ldE, float* __restrict__ rowsum,
                 const int* __restrict__ flag)
{
    __shared__ float T1t[64][65];   // T1t[a][b] = A[i0+b][j0+a]  (region1 transposed)
    __shared__ float T2t[64][65];   // T2t[a][b] = A[j0+b][i0+a]  (region2 transposed)
    const int bi = blockIdx.y, bj = blockIdx.x;
    if (bj < bi) return;
    const int isbf = flag[0];
    const int tid = threadIdx.x;
    const int i0 = bi * 64, j0 = bj * 64;
    const int tx = tid & 15;         // col group: 4 consecutive cols
    const int ty = tid >> 4;         // 0..15
    const int c0 = 4 * tx;

    // stage both regions, transposed (coalesced f32x4 global reads,
    // conflict-free scalar LDS writes)
    #pragma unroll
    for (int rr = 0; rr < 4; rr++) {
        const int rw = ty + 16 * rr;                       // 0..63
        f32x4 v1 = load4g(A, n, i0 + rw, j0 + c0, isbf);   // region1 row
        f32x4 v2 = load4g(A, n, j0 + rw, i0 + c0, isbf);   // region2 row
        #pragma unroll
        for (int k = 0; k < 4; k++) {
            T1t[c0 + k][rw] = v1[k];
            T2t[c0 + k][rw] = v2[k];
        }
    }
    __syncthreads();

    const float LOG2E = 1.442695041f;

    // ---- tile1: rows I, cols J ----
    {
        const f32x4 s4 = *(const f32x4*)&s[j0 + c0];
        #pragma unroll
        for (int q = 0; q < 4; q++) {
            const int li = ty + 16 * q;
            const int gi = i0 + li;
            const float rv = r[gi];
            const f32x4 a = load4g(A, n, gi, j0 + c0, isbf);   // L1/L2 hit (just staged)
            f32x4 ev;
            float part = 0.f;
            #pragma unroll
            for (int k = 0; k < 4; k++) {
                const float trn = T2t[li][c0 + k];             // A[gj][gi]
                const float x = a[k] * s4[k] + trn * rv;
                const float t = __builtin_amdgcn_exp2f(-x * LOG2E);   // exp(-x)
                const float sig = __builtin_amdgcn_rcpf(1.f + t);
                float e = __builtin_amdgcn_exp2f(sig * LOG2E);        // exp(sig)
                const int gj = j0 + c0 + k;
                e = (gi < n && gj < n) ? e : 0.f;
                ev[k] = e;
                part += e;
            }
            bf16x4 w;
            #pragma unroll
            for (int k = 0; k < 4; k++) w[k] = (__bf16)ev[k];
            *(bf16x4*)&E[(size_t)gi * ldE + j0 + c0] = w;
            part += __shfl_down(part, 8, 16);
            part += __shfl_down(part, 4, 16);
            part += __shfl_down(part, 2, 16);
            part += __shfl_down(part, 1, 16);
            if (tx == 0) atomicAdd(&rowsum[gi], part);
        }
    }

    // ---- tile2: rows J, cols I (skip on diagonal: tile1 already covered it) ----
    if (bj > bi) {
        const f32x4 s4 = *(const f32x4*)&s[i0 + c0];
        #pragma unroll
        for (int q = 0; q < 4; q++) {
            const int lr = ty + 16 * q;
            const int gr = j0 + lr;
            const float rv = r[gr];
            const f32x4 a = load4g(A, n, gr, i0 + c0, isbf);
            f32x4 ev;
            float part = 0.f;
            #pragma unroll
            for (int k = 0; k < 4; k++) {
                const float trn = T1t[lr][c0 + k];             // A[i0+c0+k][j0+lr] = A[gj][gr]
                const float x = a[k] * s4[k] + trn * rv;
                const float t = __builtin_amdgcn_exp2f(-x * LOG2E);
                const float sig = __builtin_amdgcn_rcpf(1.f + t);
                float e = __builtin_amdgcn_exp2f(sig * LOG2E);
                const int gj = i0 + c0 + k;
                e = (gr < n && gj < n) ? e : 0.f;
                ev[k] = e;
                part += e;
            }
            bf16x4 w;
            #pragma unroll
            for (int k = 0; k < 4; k++) w[k] = (__bf16)ev[k];
            *(bf16x4*)&E[(size_t)gr * ldE + i0 + c0] = w;
            part += __shfl_down(part, 8, 16);
            part += __shfl_down(part, 4, 16);
            part += __shfl_down(part, 2, 16);
            part += __shfl_down(part, 1, 16);
            if (tx == 0) atomicAdd(&rowsum[gr], part);
        }
    }
}

// inv over ALL nPad rows; pad rows (rowsum==0) -> 0.
__global__ void finalize_inv(const float* __restrict__ rowsum, float* __restrict__ inv, int nPad)
{
    int i = blockIdx.x * 256 + threadIdx.x;
    if (i < nPad) {
        float v = rowsum[i];
        inv[i] = v > 0.f ? 1.f / v : 0.f;
    }
}

// D (MP x 128): rows m<G from gG[c,m] (dual); rows G..M-1 from H3[m-G,c]; else 0
__global__ void build_D(const void* __restrict__ gG, const bf16* __restrict__ H3,
                        bf16* __restrict__ D, const int* __restrict__ flag)
{
    const int isbf = flag[0];
    int idx = blockIdx.x * 256 + threadIdx.x;
    int m = idx >> 7, c = idx & 127;
    float v = 0.f;
    if (c < 64) {
        if (m < N_GENES)      v = rdv(gG, (size_t)c * N_GENES + m, isbf);
        else if (m < M_NODES) v = (float)H3[(size_t)(m - N_GENES) * 128 + c];
    }
    D[idx] = (bf16)v;
}

extern "C" void kernel_launch(void* const* d_in, const int* in_sizes, int n_in,
                              void* d_out, int out_size, void* d_ws, size_t ws_size,
                              hipStream_t stream)
{
    const void* X     = d_in[0];
    const void* A_enc = d_in[1];
    const void* A_dec = d_in[2];
    const void* gG    = d_in[3];
    const void *W[7], *Wb[7], *vt[7], *vtb[7], *vr[7], *vrb[7];
    for (int l = 0; l < 7; l++) {
        W[l]   = d_in[4 + 6 * l + 0];
        Wb[l]  = d_in[4 + 6 * l + 1];
        vt[l]  = d_in[4 + 6 * l + 2];
        vtb[l] = d_in[4 + 6 * l + 3];
        vr[l]  = d_in[4 + 6 * l + 4];
        vrb[l] = d_in[4 + 6 * l + 5];
    }

    const int fop[7] = {512, 256, 128, 256, 512, 4096, 1024};
    const int fip[7] = {3072, 512, 256, 128, 256, 512, 512};
    const int foR[7] = {512, 256, 64, 256, 512, 4000, 1000};
    const int fiR[7] = {3000, 512, 256, 64, 256, 512, 512};

    // ---- workspace layout (~59 MB), small first ----
    char* ws = (char*)d_ws;
    size_t off = 0;
    auto alloc = [&](size_t bytes) -> void* {
        void* p = ws + off;
        off += (bytes + 255) & ~(size_t)255;
        return p;
    };
    int*   flag = (int*)alloc(256);
    float* sb   = (float*)alloc((size_t)MP * 4);   // sb, rb, rsum contiguous
    float* rb   = (float*)alloc((size_t)MP * 4);
    float* rsum = (float*)alloc((size_t)MP * 4);
    float* rinv = (float*)alloc((size_t)MP * 4);
    bf16* Bp[7];
    for (int l = 0; l < 7; l++) Bp[l] = (bf16*)alloc((size_t)fop[l] * 2);
    bf16* RA = (bf16*)alloc((size_t)NP * 512 * 2);   // H1 -> H3 -> D1
    bf16* RB = (bf16*)alloc((size_t)NP * 256 * 2);   // H2 -> Dd
    bf16* RC = (bf16*)alloc((size_t)MP * 512 * 2);   // D2
    bf16 *H1 = RA, *H3 = RA, *D1 = RA;
    bf16 *H2 = RB, *Dd = RB;
    bf16 *D2 = RC;
    bf16* Wp[7];
    for (int l = 0; l < 7; l++) Wp[l] = (bf16*)alloc((size_t)fop[l] * fip[l] * 2);
    bf16* ZT = (bf16*)alloc((size_t)CHMAX * MP * 2);   // 8 MB
    bf16* E  = (bf16*)alloc((size_t)MP * MP * 2);      // 32 MB
    // XT = pad(X^T) as bf16 (NP x NP, 18 MB) aliases E: it is consumed by the
    // layer-0 GEMM1 before e_pass (the first writer of E) runs.
    bf16* XT = E;

    // ---- prep ----
    sniff_dtype<<<1, 256, 0, stream>>>((const unsigned int*)X, flag);
    for (int l = 0; l < 7; l++) {
        long tot = (long)fop[l] * fip[l];
        padcopy<<<dim3((unsigned)((tot + 255) / 256)), 256, 0, stream>>>(
            W[l], foR[l], fiR[l], Wp[l], fop[l], fip[l], flag);
        padcopy<<<dim3((fop[l] + 255) / 256), 256, 0, stream>>>(
            Wb[l], 1, foR[l], Bp[l], 1, fop[l], flag);
    }
    padcopy_T<<<dim3(NP / 32, NP / 32), 256, 0, stream>>>(X, N_CELLS, XT, NP, flag);

    auto layer = [&](const bf16* Hin, int l, const void* Araw,
                     int nReal, int nPad, auto* Hout, int ldOut, int mB, int nBtot) {
        const int K = fip[l], NO = fop[l];
        const int CH = NO > CHMAX ? CHMAX : NO;
        const int nch = NO / CH;
        auto gemm1 = [&](int c) {
            gemm_nt<true, true, false, bf16><<<dim3(CH / 128, nPad / 128), 256, 0, stream>>>(
                Hin, K, Wp[l] + (size_t)c * CH * K, K, Bp[l] + c * CH, nullptr,
                ZT, nPad, K, nPad, CH);
        };
        // pass A: scores (sb, rb, rsum zeroed in one launch — contiguous)
        zero_f32<<<dim3(3 * MP / 256), 256, 0, stream>>>(sb, 3 * MP);
        for (int c = 0; c < nch; c++) {
            gemm1(c);
            int oBase = c * CH;
            int oCnt = foR[l] - oBase;
            if (oCnt > CH) oCnt = CH;
            if (oCnt > 0)
                scores_accum<<<dim3(nPad / 256, 4), 256, 0, stream>>>(
                    ZT, nPad, oBase, oCnt, vt[l], vr[l], sb, rb, flag);
        }
        scores_bias<<<dim3(nPad / 256), 256, 0, stream>>>(sb, rb, vtb[l], vrb[l], flag);
        // full E + row sums (once per layer), paired-tile kernel
        e_pass_pair<<<dim3(nPad / 64, nPad / 64), 256, 0, stream>>>(
            Araw, nReal, sb, rb, E, nPad, rsum, flag);
        finalize_inv<<<dim3(nPad / 256), 256, 0, stream>>>(rsum, rinv, nPad);
        // pass B: Hout[:, cols] = rinv[i] * (E @ Z_chunk^T), full row grid
        for (int c = 0; c < nch; c++) {
            if (nch > 1) gemm1(c);   // ZT intact when nch==1
            int colBase = c * CH;
            int nB = nBtot - colBase;
            if (nB > CH) nB = CH;
            if (nB <= 0) continue;
            gemm_nt<false, false, true><<<dim3(CH / 128, nPad / 128), 256, 0, stream>>>(
                E, nPad, ZT, nPad, nullptr, rinv,
                Hout + colBase, ldOut, nPad, mB, nB);
        }
    };

    // encoder (H0 = X^T staged as XT by padcopy_T)
    layer(XT,      0, A_enc, N_CELLS, NP, H1, 512, NP, 512);
    layer(H1,      1, A_enc, N_CELLS, NP, H2, 256, NP, 256);
    layer(H2,      2, A_enc, N_CELLS, NP, H3, 128, NP, 128);
    // decoder input D = concat([gG, H3^T], axis=1)^T
    build_D<<<dim3((MP * 128) / 256), 256, 0, stream>>>(gG, H3, Dd, flag);
    layer(Dd, 3, A_dec, M_NODES, MP, D1, 256, MP, 256);
    layer(D1, 4, A_dec, M_NODES, MP, D2, 512, MP, 512);
    // outputs are float32 (reference dtype)
    float* outCell = (float*)d_out;
    float* outGene = outCell + (size_t)M_NODES * M_NODES;
    layer(D2, 5, A_dec, M_NODES, MP, outCell, 4000, 4000, 4000);
    layer(D2, 6, A_dec, M_NODES, MP, outGene, 1000, 4000, 1000);
}

// Round 3
// 2533.746 us; speedup vs baseline: 1.2706x; 1.0169x over previous
//
#include <hip/hip_runtime.h>
#include <hip/hip_bf16.h>

using bf16 = __hip_bfloat16;
typedef __bf16 bf16x8 __attribute__((ext_vector_type(8)));
typedef __bf16 bf16x4 __attribute__((ext_vector_type(4)));
typedef float f32x4 __attribute__((ext_vector_type(4)));
typedef unsigned short u16x4 __attribute__((ext_vector_type(4)));

#define N_CELLS 3000
#define N_GENES 1000
#define M_NODES 4000
#define NP 3072
#define MP 4096
#define CHMAX 1024   // GEMM1 output-chunk columns

// dual-mode scalar read: inputs are f32 (sniffed) or bf16 (hedge)
__device__ __forceinline__ float rdv(const void* p, size_t i, int isbf) {
    if (isbf) return (float)((const bf16*)p)[i];
    return ((const float*)p)[i];
}

// guarded 4-wide row load from dual-mode matrix (n x n), zero-padded
__device__ __forceinline__ f32x4 load4g(const void* A, int n, int row, int col, int isbf) {
    f32x4 v = {0.f, 0.f, 0.f, 0.f};
    if (row < n) {
        if (col + 3 < n) {
            if (isbf) {
                const u16x4 u = *(const u16x4*)((const unsigned short*)A + (size_t)row * n + col);
                #pragma unroll
                for (int k = 0; k < 4; k++) v[k] = __uint_as_float(((unsigned)u[k]) << 16);
            } else {
                v = *(const f32x4*)((const float*)A + (size_t)row * n + col);
            }
        } else {
            #pragma unroll
            for (int k = 0; k < 4; k++)
                if (col + k < n) v[k] = rdv(A, (size_t)row * n + col + k, isbf);
        }
    }
    return v;
}

__device__ __forceinline__ void async_copy16(const bf16* g, bf16* l) {
    __builtin_amdgcn_global_load_lds((const __attribute__((address_space(1))) void*)g,
                                     (__attribute__((address_space(3))) void*)l,
                                     16, 0, 0);
}

// X ~ U[0,1): as bf16 every word's low16 < 0x3F80 (~100%); as f32 ~25%.
__global__ void sniff_dtype(const unsigned int* __restrict__ X, int* __restrict__ flag)
{
    __shared__ int cnt[4];
    int t = threadIdx.x;
    int c = 0;
    for (int i = t; i < 2048; i += 256)
        if ((X[i] & 0xFFFFu) < 0x3F80u) c++;
    #pragma unroll
    for (int off = 32; off > 0; off >>= 1) c += __shfl_down(c, off);
    if ((t & 63) == 0) cnt[t >> 6] = c;
    __syncthreads();
    if (t == 0) flag[0] = (cnt[0] + cnt[1] + cnt[2] + cnt[3] > 1536) ? 1 : 0;
}

// ---------------------------------------------------------------------------
// NT GEMM, double-buffered async global->LDS staging (T3 minimum-2-phase):
// C[i,j] = sum_k A[i,k]*B[j,k], 128x128 tile, K%32==0, bf16 in, OutT out.
// Next K-tile's loads are issued BEFORE computing the current tile, so the
// vmcnt(0) drain inside the single per-step __syncthreads happens after
// ds_read+MFMA cover (~300cy). XCD-aware bijective block swizzle (m204) keeps
// blocks sharing an A-panel on one XCD's L2.
// RELU_BIAS: C=relu(C+bias[j]). TRANS_OUT: store C[j,i]. SCALE_ROW: *rowinv[i].
// ---------------------------------------------------------------------------
template<bool RELU_BIAS, bool TRANS_OUT, bool SCALE_ROW, typename OutT>
__global__ __launch_bounds__(256, 2)
void gemm_nt(const bf16* __restrict__ A, int lda,
             const bf16* __restrict__ B, int ldb,
             const bf16* __restrict__ bias,
             const float* __restrict__ rowinv,
             OutT* __restrict__ C, int ldc,
             int K, int mBound, int nBound)
{
    __shared__ __align__(16) bf16 As[2][128 * 32];
    __shared__ __align__(16) bf16 Bs[2][128 * 32];
    const int tid  = threadIdx.x;
    const int wave = tid >> 6;
    const int lane = tid & 63;

    // bijective XCD swizzle: default HW maps linear id L -> XCD L%8; remap so
    // each XCD owns a contiguous chunk of tile-space (8 x-tiles x 4 y-tiles).
    const int nwg  = gridDim.x * gridDim.y;
    const int orig = blockIdx.y * gridDim.x + blockIdx.x;
    const int q = nwg >> 3, rr = nwg & 7;
    const int xcd = orig & 7, idx = orig >> 3;
    const int swz = (xcd < rr ? xcd * (q + 1) : rr * (q + 1) + (xcd - rr) * q) + idx;
    const int i0 = (swz / gridDim.x) * 128;
    const int j0 = (swz % gridDim.x) * 128;

    // async staging: wave w covers rows [w*32, w*32+32); lane -> (srow, 8-elem k)
    // HW writes lane i's 16B at (wave-uniform LDS base) + i*16 — layout matches.
    const int srow = lane >> 2;          // 0..15
    const int sk   = (lane & 3) * 8;     // 0,8,16,24
    const bf16* gA0 = A + (size_t)(i0 + wave * 32 + srow) * lda + sk;
    const bf16* gA1 = gA0 + (size_t)16 * lda;
    const bf16* gB0 = B + (size_t)(j0 + wave * 32 + srow) * ldb + sk;
    const bf16* gB1 = gB0 + (size_t)16 * ldb;
    const int loA0 = (wave * 32) * 32;
    const int loA1 = (wave * 32 + 16) * 32;

    const int wm = (wave >> 1) * 64;
    const int wn = (wave & 1) * 64;
    const int fr = lane & 15;
    const int fk = (lane >> 4) * 8;

    f32x4 acc[4][4] = {};

    auto stage = [&](int buf, int kt) {
        async_copy16(gA0 + kt, &As[buf][loA0]);
        async_copy16(gA1 + kt, &As[buf][loA1]);
        async_copy16(gB0 + kt, &Bs[buf][loA0]);
        async_copy16(gB1 + kt, &Bs[buf][loA1]);
    };

    stage(0, 0);
    __syncthreads();             // prologue drain (once)
    int cur = 0;

    for (int kt = 0; kt < K; kt += 32) {
        if (kt + 32 < K) stage(cur ^ 1, kt + 32);   // prefetch next tile

        bf16x8 af[4], bfv[4];
        #pragma unroll
        for (int t = 0; t < 4; t++) {
            af[t]  = *(const bf16x8*)&As[cur][(wm + t * 16 + fr) * 32 + fk];
            bfv[t] = *(const bf16x8*)&Bs[cur][(wn + t * 16 + fr) * 32 + fk];
        }
        #pragma unroll
        for (int mt = 0; mt < 4; mt++)
            #pragma unroll
            for (int nt = 0; nt < 4; nt++)
                acc[mt][nt] = __builtin_amdgcn_mfma_f32_16x16x32_bf16(
                    af[mt], bfv[nt], acc[mt][nt], 0, 0, 0);

        __syncthreads();   // vmcnt(0)+lgkmcnt(0)+barrier: prefetch landed,
                           // all reads of As[cur] done -> safe to flip
        cur ^= 1;
    }

    // C/D mapping: col(n)=lane&15, row(m)=(lane>>4)*4+reg
    const int ci = (lane >> 4) * 4;
    const int cj = lane & 15;
    #pragma unroll
    for (int nt = 0; nt < 4; nt++) {
        const int gj = j0 + wn + nt * 16 + cj;
        if (gj >= nBound) continue;
        float bv = 0.f;
        if (RELU_BIAS) bv = (float)bias[gj];
        #pragma unroll
        for (int mt = 0; mt < 4; mt++) {
            #pragma unroll
            for (int rg = 0; rg < 4; rg++) {
                const int gi = i0 + wm + mt * 16 + ci + rg;
                if (gi < mBound) {
                    float v = acc[mt][nt][rg];
                    if (RELU_BIAS) { v += bv; v = v > 0.f ? v : 0.f; }
                    if (SCALE_ROW) v *= rowinv[gi];
                    if (TRANS_OUT) C[(size_t)gj * ldc + gi] = (OutT)v;
                    else           C[(size_t)gi * ldc + gj] = (OutT)v;
                }
            }
        }
    }
}

// dst (rp x cp) bf16 = src (r x c, dual-mode) zero-padded
__global__ void padcopy(const void* __restrict__ src, int r, int c,
                        bf16* __restrict__ dst, int rp, int cp,
                        const int* __restrict__ flag)
{
    const int isbf = flag[0];
    long idx = (long)blockIdx.x * 256 + threadIdx.x;
    if (idx >= (long)rp * cp) return;
    int i = (int)(idx / cp), j = (int)(idx % cp);
    float v = 0.f;
    if (i < r && j < c) v = rdv(src, (size_t)i * c + j, isbf);
    dst[idx] = (bf16)v;
}

// XT (np x np bf16) = transpose of src (n x n, dual-mode), zero-padded.
// 32x32 LDS tile: both the global read and the global write are coalesced.
__global__ void padcopy_T(const void* __restrict__ src, int n,
                          bf16* __restrict__ dst, int np,
                          const int* __restrict__ flag)
{
    __shared__ float t[32][33];
    const int isbf = flag[0];
    const int tx = threadIdx.x & 31;
    const int ty = threadIdx.x >> 5;     // 0..7
    const int i0 = blockIdx.y * 32;      // output row block (i = src col)
    const int k0 = blockIdx.x * 32;      // output col block (k = src row)
    #pragma unroll
    for (int q = 0; q < 4; q++) {        // stage src[k0+r][i0+tx]
        int k = k0 + ty + q * 8;
        float v = 0.f;
        if (k < n && i0 + tx < n) v = rdv(src, (size_t)k * n + i0 + tx, isbf);
        t[ty + q * 8][tx] = v;
    }
    __syncthreads();
    #pragma unroll
    for (int q = 0; q < 4; q++) {        // write dst[i0+r][k0+tx] = src[k0+tx][i0+r]
        int i = ty + q * 8;
        dst[(size_t)(i0 + i) * np + k0 + tx] = (bf16)t[tx][i];
    }
}

__global__ void zero_f32(float* __restrict__ p, int n)
{
    int i = blockIdx.x * 256 + threadIdx.x;
    if (i < n) p[i] = 0.f;
}

// s[i] += sum_o Zt[o,i]*vt[oBase+o]; r likewise. Zt chunk-local (ld = nPad).
__global__ void scores_accum(const bf16* __restrict__ Zt, int ld,
                             int oBase, int oCount,
                             const void* __restrict__ vt, const void* __restrict__ vr,
                             float* __restrict__ s, float* __restrict__ r,
                             const int* __restrict__ flag)
{
    const int isbf = flag[0];
    const int i = blockIdx.x * 256 + threadIdx.x;
    const int o0 = blockIdx.y * 256;
    int o1 = o0 + 256; if (o1 > oCount) o1 = oCount;
    if (o0 >= o1) return;
    float as = 0.f, ar = 0.f;
    for (int o = o0; o < o1; o++) {
        float z = (float)Zt[(size_t)o * ld + i];
        as += z * rdv(vt, oBase + o, isbf);
        ar += z * rdv(vr, oBase + o, isbf);
    }
    atomicAdd(&s[i], as);
    atomicAdd(&r[i], ar);
}

__global__ void scores_bias(float* __restrict__ s, float* __restrict__ r,
                            const void* __restrict__ vtb, const void* __restrict__ vrb,
                            const int* __restrict__ flag)
{
    const int isbf = flag[0];
    int i = blockIdx.x * 256 + threadIdx.x;
    s[i] += rdv(vtb, 0, isbf);
    r[i] += rdv(vrb, 0, isbf);
}

// ---------------------------------------------------------------------------
// Paired E-pass: block (bi<=bj) computes E tiles (I,J) and (J,I), 64x64 each.
// E[i,j] = exp(sigmoid(A[i,j]*s[j] + A[j,i]*r[i])) for i,j<n else 0.
// Each A element is fetched by exactly one block (HBM = 1x |A|).
// Transposed terms come from LDS transposes staged at stride 65
// (bank = (row+col)%32 -> 2-way = free). Fast exp via v_exp_f32 + v_rcp_f32
// (error << bf16 rounding of E).
// ---------------------------------------------------------------------------
__global__ __launch_bounds__(256)
void e_pass_pair(const void* __restrict__ A, int n,
                 const float* __restrict__ s, const float* __restrict__ r,
                 bf16* __restrict__ E, int ldE, float* __restrict__ rowsum,
                 const int* __restrict__ flag)
{
    __shared__ float T1t[64][65];   // T1t[a][b] = A[i0+b][j0+a]  (region1 transposed)
    __shared__ float T2t[64][65];   // T2t[a][b] = A[j0+b][i0+a]  (region2 transposed)
    const int bi = blockIdx.y, bj = blockIdx.x;
    if (bj < bi) return;
    const int isbf = flag[0];
    const int tid = threadIdx.x;
    const int i0 = bi * 64, j0 = bj * 64;
    const int tx = tid & 15;         // col group: 4 consecutive cols
    const int ty = tid >> 4;         // 0..15
    const int c0 = 4 * tx;

    // stage both regions, transposed (coalesced f32x4 global reads,
    // conflict-free scalar LDS writes)
    #pragma unroll
    for (int rr = 0; rr < 4; rr++) {
        const int rw = ty + 16 * rr;                       // 0..63
        f32x4 v1 = load4g(A, n, i0 + rw, j0 + c0, isbf);   // region1 row
        f32x4 v2 = load4g(A, n, j0 + rw, i0 + c0, isbf);   // region2 row
        #pragma unroll
        for (int k = 0; k < 4; k++) {
            T1t[c0 + k][rw] = v1[k];
            T2t[c0 + k][rw] = v2[k];
        }
    }
    __syncthreads();

    const float LOG2E = 1.442695041f;

    // ---- tile1: rows I, cols J ----
    {
        const f32x4 s4 = *(const f32x4*)&s[j0 + c0];
        #pragma unroll
        for (int q = 0; q < 4; q++) {
            const int li = ty + 16 * q;
            const int gi = i0 + li;
            const float rv = r[gi];
            const f32x4 a = load4g(A, n, gi, j0 + c0, isbf);   // L1/L2 hit (just staged)
            f32x4 ev;
            float part = 0.f;
            #pragma unroll
            for (int k = 0; k < 4; k++) {
                const float trn = T2t[li][c0 + k];             // A[gj][gi]
                const float x = a[k] * s4[k] + trn * rv;
                const float t = __builtin_amdgcn_exp2f(-x * LOG2E);   // exp(-x)
                const float sig = __builtin_amdgcn_rcpf(1.f + t);
                float e = __builtin_amdgcn_exp2f(sig * LOG2E);        // exp(sig)
                const int gj = j0 + c0 + k;
                e = (gi < n && gj < n) ? e : 0.f;
                ev[k] = e;
                part += e;
            }
            bf16x4 w;
            #pragma unroll
            for (int k = 0; k < 4; k++) w[k] = (__bf16)ev[k];
            *(bf16x4*)&E[(size_t)gi * ldE + j0 + c0] = w;
            part += __shfl_down(part, 8, 16);
            part += __shfl_down(part, 4, 16);
            part += __shfl_down(part, 2, 16);
            part += __shfl_down(part, 1, 16);
            if (tx == 0) atomicAdd(&rowsum[gi], part);
        }
    }

    // ---- tile2: rows J, cols I (skip on diagonal: tile1 already covered it) ----
    if (bj > bi) {
        const f32x4 s4 = *(const f32x4*)&s[i0 + c0];
        #pragma unroll
        for (int q = 0; q < 4; q++) {
            const int lr = ty + 16 * q;
            const int gr = j0 + lr;
            const float rv = r[gr];
            const f32x4 a = load4g(A, n, gr, i0 + c0, isbf);
            f32x4 ev;
            float part = 0.f;
            #pragma unroll
            for (int k = 0; k < 4; k++) {
                const float trn = T1t[lr][c0 + k];             // A[i0+c0+k][j0+lr] = A[gj][gr]
                const float x = a[k] * s4[k] + trn * rv;
                const float t = __builtin_amdgcn_exp2f(-x * LOG2E);
                const float sig = __builtin_amdgcn_rcpf(1.f + t);
                float e = __builtin_amdgcn_exp2f(sig * LOG2E);
                const int gj = i0 + c0 + k;
                e = (gr < n && gj < n) ? e : 0.f;
                ev[k] = e;
                part += e;
            }
            bf16x4 w;
            #pragma unroll
            for (int k = 0; k < 4; k++) w[k] = (__bf16)ev[k];
            *(bf16x4*)&E[(size_t)gr * ldE + i0 + c0] = w;
            part += __shfl_down(part, 8, 16);
            part += __shfl_down(part, 4, 16);
            part += __shfl_down(part, 2, 16);
            part += __shfl_down(part, 1, 16);
            if (tx == 0) atomicAdd(&rowsum[gr], part);
        }
    }
}

// inv over ALL nPad rows; pad rows (rowsum==0) -> 0.
__global__ void finalize_inv(const float* __restrict__ rowsum, float* __restrict__ inv, int nPad)
{
    int i = blockIdx.x * 256 + threadIdx.x;
    if (i < nPad) {
        float v = rowsum[i];
        inv[i] = v > 0.f ? 1.f / v : 0.f;
    }
}

// D (MP x 128): rows m<G from gG[c,m] (dual); rows G..M-1 from H3[m-G,c]; else 0
__global__ void build_D(const void* __restrict__ gG, const bf16* __restrict__ H3,
                        bf16* __restrict__ D, const int* __restrict__ flag)
{
    const int isbf = flag[0];
    int idx = blockIdx.x * 256 + threadIdx.x;
    int m = idx >> 7, c = idx & 127;
    float v = 0.f;
    if (c < 64) {
        if (m < N_GENES)      v = rdv(gG, (size_t)c * N_GENES + m, isbf);
        else if (m < M_NODES) v = (float)H3[(size_t)(m - N_GENES) * 128 + c];
    }
    D[idx] = (bf16)v;
}

extern "C" void kernel_launch(void* const* d_in, const int* in_sizes, int n_in,
                              void* d_out, int out_size, void* d_ws, size_t ws_size,
                              hipStream_t stream)
{
    const void* X     = d_in[0];
    const void* A_enc = d_in[1];
    const void* A_dec = d_in[2];
    const void* gG    = d_in[3];
    const void *W[7], *Wb[7], *vt[7], *vtb[7], *vr[7], *vrb[7];
    for (int l = 0; l < 7; l++) {
        W[l]   = d_in[4 + 6 * l + 0];
        Wb[l]  = d_in[4 + 6 * l + 1];
        vt[l]  = d_in[4 + 6 * l + 2];
        vtb[l] = d_in[4 + 6 * l + 3];
        vr[l]  = d_in[4 + 6 * l + 4];
        vrb[l] = d_in[4 + 6 * l + 5];
    }

    const int fop[7] = {512, 256, 128, 256, 512, 4096, 1024};
    const int fip[7] = {3072, 512, 256, 128, 256, 512, 512};
    const int foR[7] = {512, 256, 64, 256, 512, 4000, 1000};
    const int fiR[7] = {3000, 512, 256, 64, 256, 512, 512};

    // ---- workspace layout (~59 MB), small first ----
    char* ws = (char*)d_ws;
    size_t off = 0;
    auto alloc = [&](size_t bytes) -> void* {
        void* p = ws + off;
        off += (bytes + 255) & ~(size_t)255;
        return p;
    };
    int*   flag = (int*)alloc(256);
    float* sb   = (float*)alloc((size_t)MP * 4);   // sb, rb, rsum contiguous
    float* rb   = (float*)alloc((size_t)MP * 4);
    float* rsum = (float*)alloc((size_t)MP * 4);
    float* rinv = (float*)alloc((size_t)MP * 4);
    bf16* Bp[7];
    for (int l = 0; l < 7; l++) Bp[l] = (bf16*)alloc((size_t)fop[l] * 2);
    bf16* RA = (bf16*)alloc((size_t)NP * 512 * 2);   // H1 -> H3 -> D1
    bf16* RB = (bf16*)alloc((size_t)NP * 256 * 2);   // H2 -> Dd
    bf16* RC = (bf16*)alloc((size_t)MP * 512 * 2);   // D2
    bf16 *H1 = RA, *H3 = RA, *D1 = RA;
    bf16 *H2 = RB, *Dd = RB;
    bf16 *D2 = RC;
    bf16* Wp[7];
    for (int l = 0; l < 7; l++) Wp[l] = (bf16*)alloc((size_t)fop[l] * fip[l] * 2);
    bf16* ZT = (bf16*)alloc((size_t)CHMAX * MP * 2);   // 8 MB
    bf16* E  = (bf16*)alloc((size_t)MP * MP * 2);      // 32 MB
    // XT = pad(X^T) as bf16 (NP x NP, 18 MB) aliases E: it is consumed by the
    // layer-0 GEMM1 before e_pass (the first writer of E) runs.
    bf16* XT = E;

    // ---- prep ----
    sniff_dtype<<<1, 256, 0, stream>>>((const unsigned int*)X, flag);
    for (int l = 0; l < 7; l++) {
        long tot = (long)fop[l] * fip[l];
        padcopy<<<dim3((unsigned)((tot + 255) / 256)), 256, 0, stream>>>(
            W[l], foR[l], fiR[l], Wp[l], fop[l], fip[l], flag);
        padcopy<<<dim3((fop[l] + 255) / 256), 256, 0, stream>>>(
            Wb[l], 1, foR[l], Bp[l], 1, fop[l], flag);
    }
    padcopy_T<<<dim3(NP / 32, NP / 32), 256, 0, stream>>>(X, N_CELLS, XT, NP, flag);

    auto layer = [&](const bf16* Hin, int l, const void* Araw,
                     int nReal, int nPad, auto* Hout, int ldOut, int mB, int nBtot) {
        const int K = fip[l], NO = fop[l];
        const int CH = NO > CHMAX ? CHMAX : NO;
        const int nch = NO / CH;
        auto gemm1 = [&](int c) {
            gemm_nt<true, true, false, bf16><<<dim3(CH / 128, nPad / 128), 256, 0, stream>>>(
                Hin, K, Wp[l] + (size_t)c * CH * K, K, Bp[l] + c * CH, nullptr,
                ZT, nPad, K, nPad, CH);
        };
        // pass A: scores (sb, rb, rsum zeroed in one launch — contiguous)
        zero_f32<<<dim3(3 * MP / 256), 256, 0, stream>>>(sb, 3 * MP);
        for (int c = 0; c < nch; c++) {
            gemm1(c);
            int oBase = c * CH;
            int oCnt = foR[l] - oBase;
            if (oCnt > CH) oCnt = CH;
            if (oCnt > 0)
                scores_accum<<<dim3(nPad / 256, 4), 256, 0, stream>>>(
                    ZT, nPad, oBase, oCnt, vt[l], vr[l], sb, rb, flag);
        }
        scores_bias<<<dim3(nPad / 256), 256, 0, stream>>>(sb, rb, vtb[l], vrb[l], flag);
        // full E + row sums (once per layer), paired-tile kernel
        e_pass_pair<<<dim3(nPad / 64, nPad / 64), 256, 0, stream>>>(
            Araw, nReal, sb, rb, E, nPad, rsum, flag);
        finalize_inv<<<dim3(nPad / 256), 256, 0, stream>>>(rsum, rinv, nPad);
        // pass B: Hout[:, cols] = rinv[i] * (E @ Z_chunk^T), full row grid
        for (int c = 0; c < nch; c++) {
            if (nch > 1) gemm1(c);   // ZT intact when nch==1
            int colBase = c * CH;
            int nB = nBtot - colBase;
            if (nB > CH) nB = CH;
            if (nB <= 0) continue;
            gemm_nt<false, false, true><<<dim3(CH / 128, nPad / 128), 256, 0, stream>>>(
                E, nPad, ZT, nPad, nullptr, rinv,
                Hout + colBase, ldOut, nPad, mB, nB);
        }
    };

    // encoder (H0 = X^T staged as XT by padcopy_T)
    layer(XT,      0, A_enc, N_CELLS, NP, H1, 512, NP, 512);
    layer(H1,      1, A_enc, N_CELLS, NP, H2, 256, NP, 256);
    layer(H2,      2, A_enc, N_CELLS, NP, H3, 128, NP, 128);
    // decoder input D = concat([gG, H3^T], axis=1)^T
    build_D<<<dim3((MP * 128) / 256), 256, 0, stream>>>(gG, H3, Dd, flag);
    layer(Dd, 3, A_dec, M_NODES, MP, D1, 256, MP, 256);
    layer(D1, 4, A_dec, M_NODES, MP, D2, 512, MP, 512);
    // outputs are float32 (reference dtype)
    float* outCell = (float*)d_out;
    float* outGene = outCell + (size_t)M_NODES * M_NODES;
    layer(D2, 5, A_dec, M_NODES, MP, outCell, 4000, 4000, 4000);
    layer(D2, 6, A_dec, M_NODES, MP, outGene, 1000, 4000, 1000);
}